// Round 11
// baseline (93.582 us; speedup 1.0000x reference)
//
#include <hip/hip_runtime.h>
#include <math.h>

// Problem constants: B=2, C=16, D=64, H=128, W=128, K=4
#define SPATIAL (64 * 128 * 128)   // 2^20 voxels per sample
#define NCLS 16
#define NB 2
#define NBLK 2048                  // 2048 blocks * 256 thr * 4 vox = 2*SPATIAL exactly
#define TPB 256

// Ledger: ticket-fused finalize +120us fixed (R2/R5) -> 2 kernels.
// float4[16] front-load -> scratch spill (R2). 8vox/thr -> occupancy crash (R6).
// chunk rotation null (R7). nt loads -7% (R9, keep). planar+LDS regression (R10).
// This round: R9 main (best) + 4-wave finalize + pinned 8 waves/SIMD.

typedef float  f32x4 __attribute__((ext_vector_type(4)));
typedef int    i32x4 __attribute__((ext_vector_type(4)));

__device__ __forceinline__ f32x4 ntload4(const float* p) {
    return __builtin_nontemporal_load(reinterpret_cast<const f32x4*>(p));
}
__device__ __forceinline__ i32x4 ntload4i(const int* p) {
    return __builtin_nontemporal_load(reinterpret_cast<const i32x4*>(p));
}

__global__ __launch_bounds__(TPB, 8) void bce_main(
    const float* __restrict__ probs,    // [B, C, SPATIAL]
    const int*   __restrict__ target,   // [B, SPATIAL]
    const int*   __restrict__ ann,      // [B, 4]
    float*       __restrict__ partials) // [5][NBLK]
{
    const int j = blockIdx.x * TPB + threadIdx.x;
    const int v = j * 4;                 // first voxel
    const int b = v >> 20;               // sample (SPATIAL = 2^20); wave-uniform
    const int s = v & (SPATIAL - 1);
    const int rot = blockIdx.x & 3;      // class-chunk rotation (free, kept)

    const float* pb = probs + (size_t)b * NCLS * SPATIAL + s;

    // Issue first prob chunk immediately (critical path), then target.
    f32x4 buf[2][4];
    {
        const int ck0 = rot;
#pragma unroll
        for (int c = 0; c < 4; ++c)
            buf[0][c] = ntload4(pb + (size_t)(ck0 * 4 + c) * SPATIAL);
    }
    const i32x4 t4 = ntload4i(target + v);
    const int t[4] = {t4.x, t4.y, t4.z, t4.w};

    // Unannotated-class bitmask (class 0 never annotated as fg); wave-uniform.
    unsigned a = 0;
#pragma unroll
    for (int k = 0; k < 4; ++k) {
        const int c = ann[b * 4 + k];
        if (c > 0) a |= (1u << c);
    }
    const unsigned m = ~a & 0xFFFFu;

    float ent[4] = {0.f, 0.f, 0.f, 0.f};
    float s0[4]  = {0.f, 0.f, 0.f, 0.f};
    float pt[4]  = {0.f, 0.f, 0.f, 0.f};

#pragma unroll
    for (int ch = 0; ch < 4; ++ch) {
        const int cur = ch & 1, nxt = cur ^ 1;
        if (ch < 3) {
            const int ckn = (ch + 1 + rot) & 3;
#pragma unroll
            for (int c = 0; c < 4; ++c)
                buf[nxt][c] = ntload4(pb + (size_t)(ckn * 4 + c) * SPATIAL);
        }
        const int ck = (ch + rot) & 3;
#pragma unroll
        for (int c = 0; c < 4; ++c) {
            const int cls = ck * 4 + c;
            const float p[4] = {buf[cur][c].x, buf[cur][c].y, buf[cur][c].z, buf[cur][c].w};
            const bool un = (m >> cls) & 1u;
#pragma unroll
            for (int q = 0; q < 4; ++q) {
                const float pc = fminf(fmaxf(p[q], 1e-6f), 0.999999f);
                ent[q] = fmaf(p[q], __log2f(pc), ent[q]);
                if (un) s0[q] += p[q];
                if (cls == t[q]) pt[q] = p[q];
            }
        }
    }

    float ce_sum = 0.f, ent_b = 0.f, cnt_b = 0.f;
#pragma unroll
    for (int q = 0; q < 4; ++q) {
        const float p  = (t[q] > 0) ? pt[q] : s0[q];
        const float pc = fminf(fmaxf(p, 1e-6f), 0.999999f);
        const float om = 1.f - p;                   // focal uses UNclamped p
        ce_sum += om * om * __log2f(pc);
        ent_b  += ent[q];
        cnt_b  += (t[q] != 0) ? 1.f : 0.f;
    }

    float vals[5];
    vals[0] = ce_sum;
    vals[1] = (b == 0) ? ent_b : 0.f;
    vals[2] = (b == 1) ? ent_b : 0.f;
    vals[3] = (b == 0) ? cnt_b : 0.f;
    vals[4] = (b == 1) ? cnt_b : 0.f;

    __shared__ float red[5][TPB / 64];
    const int lane = threadIdx.x & 63;
    const int wave = threadIdx.x >> 6;
#pragma unroll
    for (int qq = 0; qq < 5; ++qq) {
        float x = vals[qq];
#pragma unroll
        for (int off = 32; off > 0; off >>= 1)
            x += __shfl_down(x, off, 64);
        if (lane == 0) red[qq][wave] = x;
    }
    __syncthreads();
    if (threadIdx.x == 0) {
#pragma unroll
        for (int qq = 0; qq < 5; ++qq) {
            float x = 0.f;
#pragma unroll
            for (int w = 0; w < TPB / 64; ++w) x += red[qq][w];
            partials[qq * NBLK + blockIdx.x] = x;
        }
    }
}

// -------- finalize: 4 waves, parallel float4 reads, LDS cross-wave combine --------
__global__ __launch_bounds__(256) void bce_final(
    const float* __restrict__ partials, float* __restrict__ out)
{
    const int lane = threadIdx.x & 63;
    const int wave = threadIdx.x >> 6;
    __shared__ float red[5][4];

    float acc[5];
#pragma unroll
    for (int qq = 0; qq < 5; ++qq) {
        const float4* src = reinterpret_cast<const float4*>(partials + qq * NBLK);
        const float4 x = src[threadIdx.x];         // 2048 floats = 512 f4: tid, tid+256
        const float4 y = src[threadIdx.x + 256];
        acc[qq] = ((x.x + x.y) + (x.z + x.w)) + ((y.x + y.y) + (y.z + y.w));
    }
#pragma unroll
    for (int qq = 0; qq < 5; ++qq) {
        float v = acc[qq];
#pragma unroll
        for (int off = 32; off > 0; off >>= 1)
            v += __shfl_down(v, off, 64);
        if (lane == 0) red[qq][wave] = v;
    }
    __syncthreads();
    if (threadIdx.x == 0) {
        float ce = 0.f, e0 = 0.f, e1 = 0.f, c0 = 0.f, c1 = 0.f;
#pragma unroll
        for (int w = 0; w < 4; ++w) {
            ce += red[0][w]; e0 += red[1][w]; e1 += red[2][w];
            c0 += red[3][w]; c1 += red[4][w];
        }
        const float LN2  = 0.69314718055994530942f;
        const float invS = 1.f / (float)SPATIAL;
        const float ent0 = e0 * LN2 * invS;
        const float ent1 = e1 * LN2 * invS;
        const float m0   = (c0 == 0.f) ? 3.f : 1.f;   // all_bg -> MULT_UNLABELED
        const float m1   = (c1 == 0.f) ? 3.f : 1.f;
        out[0] = -(ce * LN2) / (float)(NB * SPATIAL);
        out[1] = -(m0 * ent0 + m1 * ent1) * 0.5f;
    }
}

extern "C" void kernel_launch(void* const* d_in, const int* in_sizes, int n_in,
                              void* d_out, int out_size, void* d_ws, size_t ws_size,
                              hipStream_t stream) {
    const float* probs  = (const float*)d_in[0];
    const int*   target = (const int*)d_in[1];
    const int*   ann    = (const int*)d_in[2];
    float*       out    = (float*)d_out;
    float*       partials = (float*)d_ws;   // 5 * NBLK * 4 B = 40 KiB

    bce_main<<<NBLK, TPB, 0, stream>>>(probs, target, ann, partials);
    bce_final<<<1, 256, 0, stream>>>(partials, out);
}

// Round 12
// 34.857 us; speedup vs baseline: 2.6847x; 2.6847x over previous
//
#include <hip/hip_runtime.h>
#include <math.h>

// Problem constants: B=2, C=16, D=64, H=128, W=128, K=4
#define SPATIAL (64 * 128 * 128)   // 2^20 voxels per sample
#define NCLS 16
#define NB 2
#define NBLK 2048                  // 2048 blocks * 256 thr * 4 vox = 2*SPATIAL exactly
#define TPB 256

// Ledger: ticket-fused finalize +120us fixed (R2/R5) -> 2 kernels.
// float4[16] front-load -> scratch spill (R2). 8vox/thr -> occupancy crash (R6).
// chunk rotation null (R7). nt loads -7% (R9, keep). planar+LDS regression (R10).
// __launch_bounds__(256,8) -> VGPR 64->32, 137MB scratch spill, 93us (R11):
// NEVER constrain min-waves when unconstrained alloc already hits target.
// This round: R9 main byte-identical + R11's 4-wave finalize only.

typedef float  f32x4 __attribute__((ext_vector_type(4)));
typedef int    i32x4 __attribute__((ext_vector_type(4)));

__device__ __forceinline__ f32x4 ntload4(const float* p) {
    return __builtin_nontemporal_load(reinterpret_cast<const f32x4*>(p));
}
__device__ __forceinline__ i32x4 ntload4i(const int* p) {
    return __builtin_nontemporal_load(reinterpret_cast<const i32x4*>(p));
}

__global__ __launch_bounds__(TPB) void bce_main(
    const float* __restrict__ probs,    // [B, C, SPATIAL]
    const int*   __restrict__ target,   // [B, SPATIAL]
    const int*   __restrict__ ann,      // [B, 4]
    float*       __restrict__ partials) // [5][NBLK]
{
    const int j = blockIdx.x * TPB + threadIdx.x;
    const int v = j * 4;                 // first voxel
    const int b = v >> 20;               // sample (SPATIAL = 2^20); wave-uniform
    const int s = v & (SPATIAL - 1);
    const int rot = blockIdx.x & 3;      // class-chunk rotation (free, kept)

    const i32x4 t4 = ntload4i(target + v);
    const int t[4] = {t4.x, t4.y, t4.z, t4.w};

    // Unannotated-class bitmask (class 0 never annotated as fg); wave-uniform.
    unsigned a = 0;
#pragma unroll
    for (int k = 0; k < 4; ++k) {
        const int c = ann[b * 4 + k];
        if (c > 0) a |= (1u << c);
    }
    const unsigned m = ~a & 0xFFFFu;

    const float* pb = probs + (size_t)b * NCLS * SPATIAL + s;

    float ent[4] = {0.f, 0.f, 0.f, 0.f};
    float s0[4]  = {0.f, 0.f, 0.f, 0.f};
    float pt[4]  = {0.f, 0.f, 0.f, 0.f};

    // Pipeline: buf[2][4], chunk = 4 classes, rotated start. Indices static.
    f32x4 buf[2][4];
    {
        const int ck0 = rot;
#pragma unroll
        for (int c = 0; c < 4; ++c)
            buf[0][c] = ntload4(pb + (size_t)(ck0 * 4 + c) * SPATIAL);
    }

#pragma unroll
    for (int ch = 0; ch < 4; ++ch) {
        const int cur = ch & 1, nxt = cur ^ 1;
        if (ch < 3) {
            const int ckn = (ch + 1 + rot) & 3;
#pragma unroll
            for (int c = 0; c < 4; ++c)
                buf[nxt][c] = ntload4(pb + (size_t)(ckn * 4 + c) * SPATIAL);
        }
        const int ck = (ch + rot) & 3;
#pragma unroll
        for (int c = 0; c < 4; ++c) {
            const int cls = ck * 4 + c;
            const float p[4] = {buf[cur][c].x, buf[cur][c].y, buf[cur][c].z, buf[cur][c].w};
            const bool un = (m >> cls) & 1u;
#pragma unroll
            for (int q = 0; q < 4; ++q) {
                const float pc = fminf(fmaxf(p[q], 1e-6f), 0.999999f);
                ent[q] = fmaf(p[q], __log2f(pc), ent[q]);
                if (un) s0[q] += p[q];
                if (cls == t[q]) pt[q] = p[q];
            }
        }
    }

    float ce_sum = 0.f, ent_b = 0.f, cnt_b = 0.f;
#pragma unroll
    for (int q = 0; q < 4; ++q) {
        const float p  = (t[q] > 0) ? pt[q] : s0[q];
        const float pc = fminf(fmaxf(p, 1e-6f), 0.999999f);
        const float om = 1.f - p;                   // focal uses UNclamped p
        ce_sum += om * om * __log2f(pc);
        ent_b  += ent[q];
        cnt_b  += (t[q] != 0) ? 1.f : 0.f;
    }

    float vals[5];
    vals[0] = ce_sum;
    vals[1] = (b == 0) ? ent_b : 0.f;
    vals[2] = (b == 1) ? ent_b : 0.f;
    vals[3] = (b == 0) ? cnt_b : 0.f;
    vals[4] = (b == 1) ? cnt_b : 0.f;

    __shared__ float red[5][TPB / 64];
    const int lane = threadIdx.x & 63;
    const int wave = threadIdx.x >> 6;
#pragma unroll
    for (int qq = 0; qq < 5; ++qq) {
        float x = vals[qq];
#pragma unroll
        for (int off = 32; off > 0; off >>= 1)
            x += __shfl_down(x, off, 64);
        if (lane == 0) red[qq][wave] = x;
    }
    __syncthreads();
    if (threadIdx.x == 0) {
#pragma unroll
        for (int qq = 0; qq < 5; ++qq) {
            float x = 0.f;
#pragma unroll
            for (int w = 0; w < TPB / 64; ++w) x += red[qq][w];
            partials[qq * NBLK + blockIdx.x] = x;
        }
    }
}

// -------- finalize: 4 waves, parallel float4 reads, LDS cross-wave combine --------
__global__ __launch_bounds__(256) void bce_final(
    const float* __restrict__ partials, float* __restrict__ out)
{
    const int lane = threadIdx.x & 63;
    const int wave = threadIdx.x >> 6;
    __shared__ float red[5][4];

    float acc[5];
#pragma unroll
    for (int qq = 0; qq < 5; ++qq) {
        const float4* src = reinterpret_cast<const float4*>(partials + qq * NBLK);
        const float4 x = src[threadIdx.x];         // 2048 floats = 512 f4: tid, tid+256
        const float4 y = src[threadIdx.x + 256];
        acc[qq] = ((x.x + x.y) + (x.z + x.w)) + ((y.x + y.y) + (y.z + y.w));
    }
#pragma unroll
    for (int qq = 0; qq < 5; ++qq) {
        float v = acc[qq];
#pragma unroll
        for (int off = 32; off > 0; off >>= 1)
            v += __shfl_down(v, off, 64);
        if (lane == 0) red[qq][wave] = v;
    }
    __syncthreads();
    if (threadIdx.x == 0) {
        float ce = 0.f, e0 = 0.f, e1 = 0.f, c0 = 0.f, c1 = 0.f;
#pragma unroll
        for (int w = 0; w < 4; ++w) {
            ce += red[0][w]; e0 += red[1][w]; e1 += red[2][w];
            c0 += red[3][w]; c1 += red[4][w];
        }
        const float LN2  = 0.69314718055994530942f;
        const float invS = 1.f / (float)SPATIAL;
        const float ent0 = e0 * LN2 * invS;
        const float ent1 = e1 * LN2 * invS;
        const float m0   = (c0 == 0.f) ? 3.f : 1.f;   // all_bg -> MULT_UNLABELED
        const float m1   = (c1 == 0.f) ? 3.f : 1.f;
        out[0] = -(ce * LN2) / (float)(NB * SPATIAL);
        out[1] = -(m0 * ent0 + m1 * ent1) * 0.5f;
    }
}

extern "C" void kernel_launch(void* const* d_in, const int* in_sizes, int n_in,
                              void* d_out, int out_size, void* d_ws, size_t ws_size,
                              hipStream_t stream) {
    const float* probs  = (const float*)d_in[0];
    const int*   target = (const int*)d_in[1];
    const int*   ann    = (const int*)d_in[2];
    float*       out    = (float*)d_out;
    float*       partials = (float*)d_ws;   // 5 * NBLK * 4 B = 40 KiB

    bce_main<<<NBLK, TPB, 0, stream>>>(probs, target, ann, partials);
    bce_final<<<1, 256, 0, stream>>>(partials, out);
}

// Round 13
// 33.825 us; speedup vs baseline: 2.7667x; 1.0305x over previous
//
#include <hip/hip_runtime.h>
#include <math.h>

// Problem constants: B=2, C=16, D=64, H=128, W=128, K=4
#define SPATIAL (64 * 128 * 128)   // 2^20 voxels per sample
#define NCLS 16
#define NB 2
#define NBLK 2048                  // 2048 blocks * 256 thr * 4 vox = 2*SPATIAL exactly
#define TPB 256

// FINAL (R9 lock-in, best measured 33.7us). Ledger of falsified levers:
//  - ticket-fused finalize: +120us fixed (R2/R5; device-scope fence/XCD L2 wb)
//  - float4[16] front-load: scratch spill (R2)
//  - 8 vox/thread: occupancy crash, latency-bound (R6)
//  - class-chunk rotation: null (R7; kept, free)
//  - nontemporal loads: -7% (R9; KEPT)
//  - planar+LDS restructure: regression (R10)
//  - __launch_bounds__(,8) min-waves: VGPR squeeze -> 137MB spill (R11)
//  - 4-wave finalize: null/+1.2us (R12)
// Structural ceiling: ~4.75 TB/s for the 16-stream 4MiB-stride read shape.

typedef float  f32x4 __attribute__((ext_vector_type(4)));
typedef int    i32x4 __attribute__((ext_vector_type(4)));

__device__ __forceinline__ f32x4 ntload4(const float* p) {
    return __builtin_nontemporal_load(reinterpret_cast<const f32x4*>(p));
}
__device__ __forceinline__ i32x4 ntload4i(const int* p) {
    return __builtin_nontemporal_load(reinterpret_cast<const i32x4*>(p));
}

__global__ __launch_bounds__(TPB) void bce_main(
    const float* __restrict__ probs,    // [B, C, SPATIAL]
    const int*   __restrict__ target,   // [B, SPATIAL]
    const int*   __restrict__ ann,      // [B, 4]
    float*       __restrict__ partials) // [5][NBLK]
{
    const int j = blockIdx.x * TPB + threadIdx.x;
    const int v = j * 4;                 // first voxel
    const int b = v >> 20;               // sample (SPATIAL = 2^20); wave-uniform
    const int s = v & (SPATIAL - 1);
    const int rot = blockIdx.x & 3;      // class-chunk rotation (free, kept)

    const i32x4 t4 = ntload4i(target + v);
    const int t[4] = {t4.x, t4.y, t4.z, t4.w};

    // Unannotated-class bitmask (class 0 never annotated as fg); wave-uniform.
    unsigned a = 0;
#pragma unroll
    for (int k = 0; k < 4; ++k) {
        const int c = ann[b * 4 + k];
        if (c > 0) a |= (1u << c);
    }
    const unsigned m = ~a & 0xFFFFu;

    const float* pb = probs + (size_t)b * NCLS * SPATIAL + s;

    float ent[4] = {0.f, 0.f, 0.f, 0.f};
    float s0[4]  = {0.f, 0.f, 0.f, 0.f};
    float pt[4]  = {0.f, 0.f, 0.f, 0.f};

    // Pipeline: buf[2][4], chunk = 4 classes, rotated start. Indices static.
    f32x4 buf[2][4];
    {
        const int ck0 = rot;
#pragma unroll
        for (int c = 0; c < 4; ++c)
            buf[0][c] = ntload4(pb + (size_t)(ck0 * 4 + c) * SPATIAL);
    }

#pragma unroll
    for (int ch = 0; ch < 4; ++ch) {
        const int cur = ch & 1, nxt = cur ^ 1;
        if (ch < 3) {
            const int ckn = (ch + 1 + rot) & 3;
#pragma unroll
            for (int c = 0; c < 4; ++c)
                buf[nxt][c] = ntload4(pb + (size_t)(ckn * 4 + c) * SPATIAL);
        }
        const int ck = (ch + rot) & 3;
#pragma unroll
        for (int c = 0; c < 4; ++c) {
            const int cls = ck * 4 + c;
            const float p[4] = {buf[cur][c].x, buf[cur][c].y, buf[cur][c].z, buf[cur][c].w};
            const bool un = (m >> cls) & 1u;
#pragma unroll
            for (int q = 0; q < 4; ++q) {
                const float pc = fminf(fmaxf(p[q], 1e-6f), 0.999999f);
                ent[q] = fmaf(p[q], __log2f(pc), ent[q]);
                if (un) s0[q] += p[q];
                if (cls == t[q]) pt[q] = p[q];
            }
        }
    }

    float ce_sum = 0.f, ent_b = 0.f, cnt_b = 0.f;
#pragma unroll
    for (int q = 0; q < 4; ++q) {
        const float p  = (t[q] > 0) ? pt[q] : s0[q];
        const float pc = fminf(fmaxf(p, 1e-6f), 0.999999f);
        const float om = 1.f - p;                   // focal uses UNclamped p
        ce_sum += om * om * __log2f(pc);
        ent_b  += ent[q];
        cnt_b  += (t[q] != 0) ? 1.f : 0.f;
    }

    float vals[5];
    vals[0] = ce_sum;
    vals[1] = (b == 0) ? ent_b : 0.f;
    vals[2] = (b == 1) ? ent_b : 0.f;
    vals[3] = (b == 0) ? cnt_b : 0.f;
    vals[4] = (b == 1) ? cnt_b : 0.f;

    __shared__ float red[5][TPB / 64];
    const int lane = threadIdx.x & 63;
    const int wave = threadIdx.x >> 6;
#pragma unroll
    for (int qq = 0; qq < 5; ++qq) {
        float x = vals[qq];
#pragma unroll
        for (int off = 32; off > 0; off >>= 1)
            x += __shfl_down(x, off, 64);
        if (lane == 0) red[qq][wave] = x;
    }
    __syncthreads();
    if (threadIdx.x == 0) {
#pragma unroll
        for (int qq = 0; qq < 5; ++qq) {
            float x = 0.f;
#pragma unroll
            for (int w = 0; w < TPB / 64; ++w) x += red[qq][w];
            partials[qq * NBLK + blockIdx.x] = x;
        }
    }
}

// ---------------- finalize: single wave, no barriers, float4 reads ----------------
__global__ __launch_bounds__(64) void bce_final(
    const float* __restrict__ partials, float* __restrict__ out)
{
    const int lane = threadIdx.x;   // 64 threads = 1 wave
    float acc[5] = {0.f, 0.f, 0.f, 0.f, 0.f};
#pragma unroll
    for (int qq = 0; qq < 5; ++qq) {
        const float4* src = reinterpret_cast<const float4*>(partials + qq * NBLK);
#pragma unroll
        for (int i = 0; i < 8; ++i) {
            const float4 x = src[i * 64 + lane];
            acc[qq] += (x.x + x.y) + (x.z + x.w);
        }
    }
#pragma unroll
    for (int qq = 0; qq < 5; ++qq) {
#pragma unroll
        for (int off = 32; off > 0; off >>= 1)
            acc[qq] += __shfl_down(acc[qq], off, 64);
    }
    if (lane == 0) {
        const float ce = acc[0], e0 = acc[1], e1 = acc[2], c0 = acc[3], c1 = acc[4];
        const float LN2  = 0.69314718055994530942f;
        const float invS = 1.f / (float)SPATIAL;
        const float ent0 = e0 * LN2 * invS;
        const float ent1 = e1 * LN2 * invS;
        const float m0   = (c0 == 0.f) ? 3.f : 1.f;   // all_bg -> MULT_UNLABELED
        const float m1   = (c1 == 0.f) ? 3.f : 1.f;
        out[0] = -(ce * LN2) / (float)(NB * SPATIAL);
        out[1] = -(m0 * ent0 + m1 * ent1) * 0.5f;
    }
}

extern "C" void kernel_launch(void* const* d_in, const int* in_sizes, int n_in,
                              void* d_out, int out_size, void* d_ws, size_t ws_size,
                              hipStream_t stream) {
    const float* probs  = (const float*)d_in[0];
    const int*   target = (const int*)d_in[1];
    const int*   ann    = (const int*)d_in[2];
    float*       out    = (float*)d_out;
    float*       partials = (float*)d_ws;   // 5 * NBLK * 4 B = 40 KiB

    bce_main<<<NBLK, TPB, 0, stream>>>(probs, target, ann, partials);
    bce_final<<<1, 64, 0, stream>>>(partials, out);
}